// Round 4
// baseline (1658.655 us; speedup 1.0000x reference)
//
#include <hip/hip_runtime.h>

#define NN 50000
#define EE 800000
#define DD 64
#define EDD 16
#define HH 144

typedef __attribute__((ext_vector_type(8))) __bf16 bf16x8;
typedef __attribute__((ext_vector_type(4))) float f32x4;
typedef __attribute__((ext_vector_type(8))) unsigned short ushort8;

__device__ __forceinline__ unsigned short f2bf(float f) {
  unsigned u = __float_as_uint(f);
  unsigned r = u + 0x7fffu + ((u >> 16) & 1u);
  return (unsigned short)(r >> 16);
}

// ---- convert edge_idx (int64 OR int32 storage, runtime-detected) ----
__global__ __launch_bounds__(256) void cvt_idx(const unsigned* eidx, int* srcA, int* dstA) {
  int i = blockIdx.x * 256 + threadIdx.x;
  unsigned acc = 0;
#pragma unroll
  for (int k = 0; k < 32; k++) acc |= eidx[2 * k + 1];
  bool is64 = (acc == 0);
  if (i < EE) {
    if (is64) {
      srcA[i] = (int)eidx[2 * i];
      dstA[i] = (int)eidx[2 * (EE + i)];
    } else {
      srcA[i] = (int)eidx[i];
      dstA[i] = (int)eidx[EE + i];
    }
  }
}

// ---- pack W1 (att MLP) into bf16 B-frag order; pad b1/W2 to 160 ----
__global__ __launch_bounds__(256) void pack_w1(const float* __restrict__ W1,
                                               const float* __restrict__ b1,
                                               const float* __restrict__ W2,
                                               unsigned short* __restrict__ Bpk,
                                               float* __restrict__ b1p,
                                               float* __restrict__ w2p) {
  int id = blockIdx.x * 256 + threadIdx.x;
  if (id < 3200) {  // 10 ntiles * 5 ksteps * 64 lanes
    int l = id & 63, q = id >> 6;
    int nt = q / 5, ks = q - 5 * nt;
    int j = nt * 16 + (l & 15);
    int k0 = ks * 32 + ((l >> 4) << 3);
    ushort8 pk;
#pragma unroll
    for (int i = 0; i < 8; i++) {
      int k = k0 + i;
      float f = (j < HH && k < HH) ? W1[j * HH + k] : 0.f;
      pk[i] = f2bf(f);
    }
    *(ushort8*)&Bpk[id * 8] = pk;
  }
  if (id < 160) {
    b1p[id] = (id < HH) ? b1[id] : 0.f;
    w2p[id] = (id < HH) ? W2[id] : 0.f;
  }
}

// ---- pack GRU weights: B = [Wih (ks 0,1) | Whh (ks 2,3)], 12 n-tiles x 4 k-steps ----
__global__ __launch_bounds__(256) void pack_gru(const float* __restrict__ Wih,
                                                const float* __restrict__ Whh,
                                                unsigned short* __restrict__ Bg) {
  int id = blockIdx.x * 256 + threadIdx.x;
  if (id >= 3072) return;
  int l = id & 63, q = id >> 6;  // q = nt*4 + ks
  int nt = q >> 2, ks = q & 3;
  int j = nt * 16 + (l & 15);
  int k0 = ((l >> 4) << 3);
  const float* Wsrc = (ks < 2) ? (Wih + (size_t)j * 64 + ks * 32 + k0)
                               : (Whh + (size_t)j * 64 + (ks - 2) * 32 + k0);
  ushort8 pk;
#pragma unroll
  for (int i = 0; i < 8; i++) pk[i] = f2bf(Wsrc[i]);
  *(ushort8*)&Bg[id * 8] = pk;
}

// ---- lin_x = x @ W_lin^T + b_lin ----
__global__ __launch_bounds__(256) void lin_kernel(const float* __restrict__ x,
                                                  const float* __restrict__ W,
                                                  const float* __restrict__ b,
                                                  float* __restrict__ lin_x) {
  __shared__ float w_lds[64 * 65];
  __shared__ float b_lds[64];
  int t = threadIdx.x;
  for (int i = t; i < 4096; i += 256) {
    int j = i >> 6, k = i & 63;
    w_lds[j * 65 + k] = W[i];
  }
  if (t < 64) b_lds[t] = b[t];
  __syncthreads();
  int lane = t & 63, wv = t >> 6;
  int node = blockIdx.x * 4 + wv;
  if (node >= NN) return;
  const float* xr = x + (size_t)node * 64;
  float acc = b_lds[lane];
#pragma unroll
  for (int k = 0; k < 64; k++) acc += w_lds[lane * 65 + k] * xr[k];
  lin_x[(size_t)node * 64 + lane] = acc;
}

// ---- per-edge attention scores via bf16 MFMA ----
__global__ __launch_bounds__(256) void att_mfma(const float* __restrict__ x,
                                                const float* __restrict__ ew,
                                                const int* __restrict__ srcA,
                                                const int* __restrict__ dstA,
                                                const unsigned short* __restrict__ Bpk,
                                                const float* __restrict__ b1p,
                                                const float* __restrict__ w2p,
                                                const float* __restrict__ b2,
                                                float* __restrict__ scores) {
  __shared__ unsigned short fl[640 * 8];
  __shared__ float sc[32];
  int t = threadIdx.x;
  int lane = t & 63, w = t >> 6;
  int tile = w >> 1, h = w & 1;

  bf16x8 Bf[25];
#pragma unroll
  for (int q = 0; q < 25; q++) {
    int nt = h * 5 + q / 5, ks = q % 5;
    Bf[q] = *(const bf16x8*)&Bpk[((nt * 5 + ks) * 64 + lane) * 8];
  }
  float b1v[5], w2v[5];
#pragma unroll
  for (int n = 0; n < 5; n++) {
    int j = (h * 5 + n) * 16 + (lane & 15);
    b1v[n] = b1p[j];
    w2v[n] = w2p[j];
  }
  float b2v = b2[0];

  for (int pair = blockIdx.x; pair < EE / 32; pair += gridDim.x) {
    int ebase = pair * 32;
    for (int fid = t; fid < 640; fid += 256) {
      int l = fid & 63, q = fid >> 6;
      int ti = q / 5, ks = q - 5 * ti;
      int e = ebase + ti * 16 + (l & 15);
      int k0 = ks * 32 + ((l >> 4) << 3);
      float4 v0, v1;
      if (k0 < 64) {
        const float4* p = (const float4*)(x + (size_t)srcA[e] * 64 + k0);
        v0 = p[0]; v1 = p[1];
      } else if (k0 < 80) {
        const float4* p = (const float4*)(ew + (size_t)e * 16 + (k0 - 64));
        v0 = p[0]; v1 = p[1];
      } else if (k0 < 144) {
        const float4* p = (const float4*)(x + (size_t)dstA[e] * 64 + (k0 - 80));
        v0 = p[0]; v1 = p[1];
      } else {
        v0 = make_float4(0.f, 0.f, 0.f, 0.f); v1 = v0;
      }
      ushort8 pk;
      pk[0] = f2bf(v0.x); pk[1] = f2bf(v0.y); pk[2] = f2bf(v0.z); pk[3] = f2bf(v0.w);
      pk[4] = f2bf(v1.x); pk[5] = f2bf(v1.y); pk[6] = f2bf(v1.z); pk[7] = f2bf(v1.w);
      *(ushort8*)&fl[fid * 8] = pk;
    }
    if (t < 32) sc[t] = b2v;
    __syncthreads();
    f32x4 acc[5] = {};
    bf16x8 a[5];
#pragma unroll
    for (int ks = 0; ks < 5; ks++)
      a[ks] = *(const bf16x8*)&fl[((tile * 5 + ks) * 64 + lane) * 8];
#pragma unroll
    for (int ks = 0; ks < 5; ks++)
#pragma unroll
      for (int n = 0; n < 5; n++)
        acc[n] = __builtin_amdgcn_mfma_f32_16x16x32_bf16(a[ks], Bf[n * 5 + ks], acc[n], 0, 0, 0);
    float part[4] = {0.f, 0.f, 0.f, 0.f};
#pragma unroll
    for (int n = 0; n < 5; n++) {
#pragma unroll
      for (int r = 0; r < 4; r++)
        part[r] += fmaxf(acc[n][r] + b1v[n], 0.f) * w2v[n];
    }
#pragma unroll
    for (int m = 1; m < 16; m <<= 1) {
#pragma unroll
      for (int r = 0; r < 4; r++) part[r] += __shfl_xor(part[r], m);
    }
    if ((lane & 15) == 0) {
      int er = tile * 16 + ((lane >> 4) << 2);
#pragma unroll
      for (int r = 0; r < 4; r++) atomicAdd(&sc[er + r], part[r]);
    }
    __syncthreads();
    if (t < 32) scores[ebase + t] = sc[t];
  }
}

// ---- fused softmax+message, NO max-shift (scores bounded ~±1.5):
// e = exp(s); denom += e; msgU += e * lin_x[dst]. 32 edges per wave-iteration,
// 4 unrolled batches of 8 edges for ILP. lane = edge-slot(j)*8 + dim-group(g).
__global__ __launch_bounds__(256) void exp_msg(const float* __restrict__ scores,
                                               const int* __restrict__ srcA,
                                               const int* __restrict__ dstA,
                                               const float* __restrict__ lin_x,
                                               float* __restrict__ denom,
                                               float* __restrict__ msgU) {
  int lane = threadIdx.x & 63;
  int gw = (blockIdx.x * 256 + threadIdx.x) >> 6;  // global wave id
  int nw = (gridDim.x * 256) >> 6;
  int j = lane >> 3, g = lane & 7;
  for (int base = gw * 32; base < EE; base += nw * 32) {
    int s[4], d[4];
    float ev[4];
#pragma unroll
    for (int b = 0; b < 4; b++) {
      int e = base + b * 8 + j;
      s[b] = srcA[e];
      d[b] = dstA[e];
      ev[b] = scores[e];
    }
#pragma unroll
    for (int b = 0; b < 4; b++) ev[b] = __expf(ev[b]);
    float4 v0[4], v1[4];
#pragma unroll
    for (int b = 0; b < 4; b++) {
      const float4* lp = (const float4*)(lin_x + (size_t)d[b] * 64 + g * 8);
      v0[b] = lp[0];
      v1[b] = lp[1];
    }
#pragma unroll
    for (int b = 0; b < 4; b++) {
      if (g == 0) atomicAdd(&denom[s[b]], ev[b]);
      float* mp = msgU + (size_t)s[b] * 64 + g * 8;
      atomicAdd(&mp[0], ev[b] * v0[b].x);
      atomicAdd(&mp[1], ev[b] * v0[b].y);
      atomicAdd(&mp[2], ev[b] * v0[b].z);
      atomicAdd(&mp[3], ev[b] * v0[b].w);
      atomicAdd(&mp[4], ev[b] * v1[b].x);
      atomicAdd(&mp[5], ev[b] * v1[b].y);
      atomicAdd(&mp[6], ev[b] * v1[b].z);
      atomicAdd(&mp[7], ev[b] * v1[b].w);
    }
  }
}

// ---- GRU via MFMA: S = [x|msg] @ [Wih|Whh]^T, fused gates ----
__global__ __launch_bounds__(256) void gru_mfma(const float* __restrict__ x,
                                                const float* __restrict__ msgU,
                                                const float* __restrict__ denom,
                                                const unsigned short* __restrict__ Bg,
                                                const float* __restrict__ bih,
                                                const float* __restrict__ bhh,
                                                float* __restrict__ out) {
  __shared__ unsigned short afrag[512 * 8];
  __shared__ float S[32 * 196];
  __shared__ float SHn[32 * 68];
  int t = threadIdx.x;
  int lane = t & 63, w = t >> 6;
  int base = blockIdx.x * 32;

  bf16x8 Bf[3][4];
#pragma unroll
  for (int q = 0; q < 3; q++)
#pragma unroll
    for (int ks = 0; ks < 4; ks++)
      Bf[q][ks] = *(const bf16x8*)&Bg[(((3 * w + q) * 4 + ks) * 64 + lane) * 8];

  int n = t >> 3;
  int d0 = (t & 7) * 8;
  int node = base + n;
  bool valid = node < NN;
  float xv[8], mv[8];
  float dn = 0.f;
  if (valid) {
    const float4* xp = (const float4*)(x + (size_t)node * 64 + d0);
    float4 x0 = xp[0], x1 = xp[1];
    xv[0] = x0.x; xv[1] = x0.y; xv[2] = x0.z; xv[3] = x0.w;
    xv[4] = x1.x; xv[5] = x1.y; xv[6] = x1.z; xv[7] = x1.w;
    dn = denom[node];
    float inv = (dn > 0.f) ? 1.f / dn : 0.f;
    const float4* mp = (const float4*)(msgU + (size_t)node * 64 + d0);
    float4 m0 = mp[0], m1 = mp[1];
    mv[0] = m0.x * inv; mv[1] = m0.y * inv; mv[2] = m0.z * inv; mv[3] = m0.w * inv;
    mv[4] = m1.x * inv; mv[5] = m1.y * inv; mv[6] = m1.z * inv; mv[7] = m1.w * inv;
  } else {
#pragma unroll
    for (int i = 0; i < 8; i++) { xv[i] = 0.f; mv[i] = 0.f; }
  }
  {
    int ti = n >> 4, r = n & 15, ksx = d0 >> 5, sub = (d0 >> 3) & 3;
    ushort8 px, pm;
#pragma unroll
    for (int i = 0; i < 8; i++) { px[i] = f2bf(xv[i]); pm[i] = f2bf(mv[i]); }
    *(ushort8*)&afrag[((ti * 4 + ksx) * 64 + sub * 16 + r) * 8] = px;
    *(ushort8*)&afrag[((ti * 4 + 2 + ksx) * 64 + sub * 16 + r) * 8] = pm;
  }
  __syncthreads();

  bf16x8 a[2][4];
#pragma unroll
  for (int ti = 0; ti < 2; ti++)
#pragma unroll
    for (int ks = 0; ks < 4; ks++)
      a[ti][ks] = *(const bf16x8*)&afrag[((ti * 4 + ks) * 64 + lane) * 8];
#pragma unroll
  for (int q = 0; q < 3; q++) {
    int nt = 3 * w + q;
    int jcol = nt * 16 + (lane & 15);
#pragma unroll
    for (int ti = 0; ti < 2; ti++) {
      f32x4 accA = {}, accB = {};
      accA = __builtin_amdgcn_mfma_f32_16x16x32_bf16(a[ti][0], Bf[q][0], accA, 0, 0, 0);
      accA = __builtin_amdgcn_mfma_f32_16x16x32_bf16(a[ti][1], Bf[q][1], accA, 0, 0, 0);
      accB = __builtin_amdgcn_mfma_f32_16x16x32_bf16(a[ti][2], Bf[q][2], accB, 0, 0, 0);
      accB = __builtin_amdgcn_mfma_f32_16x16x32_bf16(a[ti][3], Bf[q][3], accB, 0, 0, 0);
      int nrow = ti * 16 + ((lane >> 4) << 2);
      if (nt < 8) {
#pragma unroll
        for (int rr = 0; rr < 4; rr++) S[(nrow + rr) * 196 + jcol] = accA[rr] + accB[rr];
      } else {
#pragma unroll
        for (int rr = 0; rr < 4; rr++) {
          S[(nrow + rr) * 196 + jcol] = accA[rr];
          SHn[(nrow + rr) * 68 + (jcol - 128)] = accB[rr];
        }
      }
    }
  }
  __syncthreads();

  if (valid) {
    float res[8];
#pragma unroll
    for (int jj = 0; jj < 8; jj++) {
      int j = d0 + jj;
      float gr = S[n * 196 + j] + bih[j] + bhh[j];
      float gz = S[n * 196 + 64 + j] + bih[64 + j] + bhh[64 + j];
      float gin = S[n * 196 + 128 + j] + bih[128 + j];
      float ghn = SHn[n * 68 + j] + bhh[128 + j];
      float rg = 1.f / (1.f + __expf(-gr));
      float zg = 1.f / (1.f + __expf(-gz));
      float ng = tanhf(gin + rg * ghn);
      float h = (1.f - zg) * ng + zg * mv[jj];
      res[jj] = (dn > 0.f) ? h : xv[jj];
    }
    float4* op = (float4*)(out + (size_t)node * 64 + d0);
    op[0] = make_float4(res[0], res[1], res[2], res[3]);
    op[1] = make_float4(res[4], res[5], res[6], res[7]);
  }
}

extern "C" void kernel_launch(void* const* d_in, const int* in_sizes, int n_in,
                              void* d_out, int out_size, void* d_ws, size_t ws_size,
                              hipStream_t stream) {
  const float* x = (const float*)d_in[0];
  const unsigned* eidx = (const unsigned*)d_in[1];
  const float* ew = (const float*)d_in[2];
  const float* W1 = (const float*)d_in[3];
  const float* b1 = (const float*)d_in[4];
  const float* W2 = (const float*)d_in[5];
  const float* b2 = (const float*)d_in[6];
  const float* Wl = (const float*)d_in[7];
  const float* bl = (const float*)d_in[8];
  const float* Wih = (const float*)d_in[9];
  const float* bih = (const float*)d_in[10];
  const float* Whh = (const float*)d_in[11];
  const float* bhh = (const float*)d_in[12];
  float* out = (float*)d_out;

  float* lin_x = (float*)d_ws;                 // N*D
  float* scores = lin_x + (size_t)NN * DD;     // E
  int* srcA = (int*)(scores + EE);             // E
  int* dstA = srcA + EE;                       // E
  float* msgU = (float*)(dstA + EE);           // N*D
  float* denom = msgU + (size_t)NN * DD;       // N
  unsigned short* Bpk = (unsigned short*)(denom + NN);    // 3200*8
  float* b1p = (float*)(Bpk + 25600);          // 160
  float* w2p = b1p + 160;                      // 160
  unsigned short* Bg = (unsigned short*)(w2p + 160);      // 3072*8

  // zero msgU | denom (contiguous)
  hipMemsetAsync(msgU, 0, (size_t)(NN * DD + NN) * sizeof(float), stream);

  cvt_idx<<<(EE + 255) / 256, 256, 0, stream>>>(eidx, srcA, dstA);
  pack_w1<<<13, 256, 0, stream>>>(W1, b1, W2, Bpk, b1p, w2p);
  pack_gru<<<12, 256, 0, stream>>>(Wih, Whh, Bg);
  lin_kernel<<<(NN + 3) / 4, 256, 0, stream>>>(x, Wl, bl, lin_x);
  att_mfma<<<2048, 256, 0, stream>>>(x, ew, srcA, dstA, Bpk, b1p, w2p, b2, scores);
  exp_msg<<<2048, 256, 0, stream>>>(scores, srcA, dstA, lin_x, denom, msgU);
  gru_mfma<<<(NN + 31) / 32, 256, 0, stream>>>(x, msgU, denom, Bg, bih, bhh, out);
}

// Round 5
// 431.750 us; speedup vs baseline: 3.8417x; 3.8417x over previous
//
#include <hip/hip_runtime.h>

#define NN 50000
#define EE 800000
#define DD 64
#define EDD 16
#define HH 144

typedef __attribute__((ext_vector_type(8))) __bf16 bf16x8;
typedef __attribute__((ext_vector_type(4))) float f32x4;
typedef __attribute__((ext_vector_type(8))) unsigned short ushort8;

__device__ __forceinline__ unsigned short f2bf(float f) {
  unsigned u = __float_as_uint(f);
  unsigned r = u + 0x7fffu + ((u >> 16) & 1u);
  return (unsigned short)(r >> 16);
}

// ---- convert edge_idx (int64 OR int32 storage, runtime-detected) ----
__global__ __launch_bounds__(256) void cvt_idx(const unsigned* eidx, int* srcA, int* dstA) {
  int i = blockIdx.x * 256 + threadIdx.x;
  unsigned acc = 0;
#pragma unroll
  for (int k = 0; k < 32; k++) acc |= eidx[2 * k + 1];
  bool is64 = (acc == 0);
  if (i < EE) {
    if (is64) {
      srcA[i] = (int)eidx[2 * i];
      dstA[i] = (int)eidx[2 * (EE + i)];
    } else {
      srcA[i] = (int)eidx[i];
      dstA[i] = (int)eidx[EE + i];
    }
  }
}

// ---- pack W1 (att MLP) into bf16 B-frag order; pad b1/W2 to 160 ----
__global__ __launch_bounds__(256) void pack_w1(const float* __restrict__ W1,
                                               const float* __restrict__ b1,
                                               const float* __restrict__ W2,
                                               unsigned short* __restrict__ Bpk,
                                               float* __restrict__ b1p,
                                               float* __restrict__ w2p) {
  int id = blockIdx.x * 256 + threadIdx.x;
  if (id < 3200) {  // 10 ntiles * 5 ksteps * 64 lanes
    int l = id & 63, q = id >> 6;
    int nt = q / 5, ks = q - 5 * nt;
    int j = nt * 16 + (l & 15);
    int k0 = ks * 32 + ((l >> 4) << 3);
    ushort8 pk;
#pragma unroll
    for (int i = 0; i < 8; i++) {
      int k = k0 + i;
      float f = (j < HH && k < HH) ? W1[j * HH + k] : 0.f;
      pk[i] = f2bf(f);
    }
    *(ushort8*)&Bpk[id * 8] = pk;
  }
  if (id < 160) {
    b1p[id] = (id < HH) ? b1[id] : 0.f;
    w2p[id] = (id < HH) ? W2[id] : 0.f;
  }
}

// ---- pack GRU weights: B = [Wih (ks 0,1) | Whh (ks 2,3)], 12 n-tiles x 4 k-steps ----
__global__ __launch_bounds__(256) void pack_gru(const float* __restrict__ Wih,
                                                const float* __restrict__ Whh,
                                                unsigned short* __restrict__ Bg) {
  int id = blockIdx.x * 256 + threadIdx.x;
  if (id >= 3072) return;
  int l = id & 63, q = id >> 6;  // q = nt*4 + ks
  int nt = q >> 2, ks = q & 3;
  int j = nt * 16 + (l & 15);
  int k0 = ((l >> 4) << 3);
  const float* Wsrc = (ks < 2) ? (Wih + (size_t)j * 64 + ks * 32 + k0)
                               : (Whh + (size_t)j * 64 + (ks - 2) * 32 + k0);
  ushort8 pk;
#pragma unroll
  for (int i = 0; i < 8; i++) pk[i] = f2bf(Wsrc[i]);
  *(ushort8*)&Bg[id * 8] = pk;
}

// ---- lin_x = x @ W_lin^T + b_lin ----
__global__ __launch_bounds__(256) void lin_kernel(const float* __restrict__ x,
                                                  const float* __restrict__ W,
                                                  const float* __restrict__ b,
                                                  float* __restrict__ lin_x) {
  __shared__ float w_lds[64 * 65];
  __shared__ float b_lds[64];
  int t = threadIdx.x;
  for (int i = t; i < 4096; i += 256) {
    int j = i >> 6, k = i & 63;
    w_lds[j * 65 + k] = W[i];
  }
  if (t < 64) b_lds[t] = b[t];
  __syncthreads();
  int lane = t & 63, wv = t >> 6;
  int node = blockIdx.x * 4 + wv;
  if (node >= NN) return;
  const float* xr = x + (size_t)node * 64;
  float acc = b_lds[lane];
#pragma unroll
  for (int k = 0; k < 64; k++) acc += w_lds[lane * 65 + k] * xr[k];
  lin_x[(size_t)node * 64 + lane] = acc;
}

// ---- per-edge attention scores via bf16 MFMA ----
__global__ __launch_bounds__(256) void att_mfma(const float* __restrict__ x,
                                                const float* __restrict__ ew,
                                                const int* __restrict__ srcA,
                                                const int* __restrict__ dstA,
                                                const unsigned short* __restrict__ Bpk,
                                                const float* __restrict__ b1p,
                                                const float* __restrict__ w2p,
                                                const float* __restrict__ b2,
                                                float* __restrict__ scores) {
  __shared__ unsigned short fl[640 * 8];
  __shared__ float sc[32];
  int t = threadIdx.x;
  int lane = t & 63, w = t >> 6;
  int tile = w >> 1, h = w & 1;

  bf16x8 Bf[25];
#pragma unroll
  for (int q = 0; q < 25; q++) {
    int nt = h * 5 + q / 5, ks = q % 5;
    Bf[q] = *(const bf16x8*)&Bpk[((nt * 5 + ks) * 64 + lane) * 8];
  }
  float b1v[5], w2v[5];
#pragma unroll
  for (int n = 0; n < 5; n++) {
    int j = (h * 5 + n) * 16 + (lane & 15);
    b1v[n] = b1p[j];
    w2v[n] = w2p[j];
  }
  float b2v = b2[0];

  for (int pair = blockIdx.x; pair < EE / 32; pair += gridDim.x) {
    int ebase = pair * 32;
    for (int fid = t; fid < 640; fid += 256) {
      int l = fid & 63, q = fid >> 6;
      int ti = q / 5, ks = q - 5 * ti;
      int e = ebase + ti * 16 + (l & 15);
      int k0 = ks * 32 + ((l >> 4) << 3);
      float4 v0, v1;
      if (k0 < 64) {
        const float4* p = (const float4*)(x + (size_t)srcA[e] * 64 + k0);
        v0 = p[0]; v1 = p[1];
      } else if (k0 < 80) {
        const float4* p = (const float4*)(ew + (size_t)e * 16 + (k0 - 64));
        v0 = p[0]; v1 = p[1];
      } else if (k0 < 144) {
        const float4* p = (const float4*)(x + (size_t)dstA[e] * 64 + (k0 - 80));
        v0 = p[0]; v1 = p[1];
      } else {
        v0 = make_float4(0.f, 0.f, 0.f, 0.f); v1 = v0;
      }
      ushort8 pk;
      pk[0] = f2bf(v0.x); pk[1] = f2bf(v0.y); pk[2] = f2bf(v0.z); pk[3] = f2bf(v0.w);
      pk[4] = f2bf(v1.x); pk[5] = f2bf(v1.y); pk[6] = f2bf(v1.z); pk[7] = f2bf(v1.w);
      *(ushort8*)&fl[fid * 8] = pk;
    }
    if (t < 32) sc[t] = b2v;
    __syncthreads();
    f32x4 acc[5] = {};
    bf16x8 a[5];
#pragma unroll
    for (int ks = 0; ks < 5; ks++)
      a[ks] = *(const bf16x8*)&fl[((tile * 5 + ks) * 64 + lane) * 8];
#pragma unroll
    for (int ks = 0; ks < 5; ks++)
#pragma unroll
      for (int n = 0; n < 5; n++)
        acc[n] = __builtin_amdgcn_mfma_f32_16x16x32_bf16(a[ks], Bf[n * 5 + ks], acc[n], 0, 0, 0);
    float part[4] = {0.f, 0.f, 0.f, 0.f};
#pragma unroll
    for (int n = 0; n < 5; n++) {
#pragma unroll
      for (int r = 0; r < 4; r++)
        part[r] += fmaxf(acc[n][r] + b1v[n], 0.f) * w2v[n];
    }
#pragma unroll
    for (int m = 1; m < 16; m <<= 1) {
#pragma unroll
      for (int r = 0; r < 4; r++) part[r] += __shfl_xor(part[r], m);
    }
    if ((lane & 15) == 0) {
      int er = tile * 16 + ((lane >> 4) << 2);
#pragma unroll
      for (int r = 0; r < 4; r++) atomicAdd(&sc[er + r], part[r]);
    }
    __syncthreads();
    if (t < 32) scores[ebase + t] = sc[t];
  }
}

// ---- fused softmax+message, no max-shift. 8 edges per wave-iteration; each
// edge handled by the FULL wave so the gather and the atomicAdd are 64x4B
// contiguous per instruction (atomics merge sectors only within one instr;
// scalar per-lane atomics caused 32B-granule 1.6GB HBM write amplification). ----
__global__ __launch_bounds__(256) void exp_msg(const float* __restrict__ scores,
                                               const int* __restrict__ srcA,
                                               const int* __restrict__ dstA,
                                               const float* __restrict__ lin_x,
                                               float* __restrict__ denom,
                                               float* __restrict__ msgU) {
  int lane = threadIdx.x & 63;
  int gw = (blockIdx.x * 256 + threadIdx.x) >> 6;  // global wave id
  int nw = (gridDim.x * 256) >> 6;
  for (int base = gw * 8; base < EE; base += nw * 8) {
    int s[8], d[8];
    float ev[8];
#pragma unroll
    for (int b = 0; b < 8; b++) {
      s[b] = srcA[base + b];
      d[b] = dstA[base + b];
      ev[b] = scores[base + b];
    }
#pragma unroll
    for (int b = 0; b < 8; b++) ev[b] = __expf(ev[b]);
    float v[8];
#pragma unroll
    for (int b = 0; b < 8; b++) v[b] = lin_x[(size_t)d[b] * 64 + lane];
#pragma unroll
    for (int b = 0; b < 8; b++) {
      atomicAdd(&msgU[(size_t)s[b] * 64 + lane], ev[b] * v[b]);
      if (lane == b * 8) atomicAdd(&denom[s[b]], ev[b]);
    }
  }
}

// ---- GRU via MFMA: S = [x|msg] @ [Wih|Whh]^T, fused gates ----
__global__ __launch_bounds__(256) void gru_mfma(const float* __restrict__ x,
                                                const float* __restrict__ msgU,
                                                const float* __restrict__ denom,
                                                const unsigned short* __restrict__ Bg,
                                                const float* __restrict__ bih,
                                                const float* __restrict__ bhh,
                                                float* __restrict__ out) {
  __shared__ unsigned short afrag[512 * 8];
  __shared__ float S[32 * 196];
  __shared__ float SHn[32 * 68];
  int t = threadIdx.x;
  int lane = t & 63, w = t >> 6;
  int base = blockIdx.x * 32;

  bf16x8 Bf[3][4];
#pragma unroll
  for (int q = 0; q < 3; q++)
#pragma unroll
    for (int ks = 0; ks < 4; ks++)
      Bf[q][ks] = *(const bf16x8*)&Bg[(((3 * w + q) * 4 + ks) * 64 + lane) * 8];

  int n = t >> 3;
  int d0 = (t & 7) * 8;
  int node = base + n;
  bool valid = node < NN;
  float xv[8], mv[8];
  float dn = 0.f;
  if (valid) {
    const float4* xp = (const float4*)(x + (size_t)node * 64 + d0);
    float4 x0 = xp[0], x1 = xp[1];
    xv[0] = x0.x; xv[1] = x0.y; xv[2] = x0.z; xv[3] = x0.w;
    xv[4] = x1.x; xv[5] = x1.y; xv[6] = x1.z; xv[7] = x1.w;
    dn = denom[node];
    float inv = (dn > 0.f) ? 1.f / dn : 0.f;
    const float4* mp = (const float4*)(msgU + (size_t)node * 64 + d0);
    float4 m0 = mp[0], m1 = mp[1];
    mv[0] = m0.x * inv; mv[1] = m0.y * inv; mv[2] = m0.z * inv; mv[3] = m0.w * inv;
    mv[4] = m1.x * inv; mv[5] = m1.y * inv; mv[6] = m1.z * inv; mv[7] = m1.w * inv;
  } else {
#pragma unroll
    for (int i = 0; i < 8; i++) { xv[i] = 0.f; mv[i] = 0.f; }
  }
  {
    int ti = n >> 4, r = n & 15, ksx = d0 >> 5, sub = (d0 >> 3) & 3;
    ushort8 px, pm;
#pragma unroll
    for (int i = 0; i < 8; i++) { px[i] = f2bf(xv[i]); pm[i] = f2bf(mv[i]); }
    *(ushort8*)&afrag[((ti * 4 + ksx) * 64 + sub * 16 + r) * 8] = px;
    *(ushort8*)&afrag[((ti * 4 + 2 + ksx) * 64 + sub * 16 + r) * 8] = pm;
  }
  __syncthreads();

  bf16x8 a[2][4];
#pragma unroll
  for (int ti = 0; ti < 2; ti++)
#pragma unroll
    for (int ks = 0; ks < 4; ks++)
      a[ti][ks] = *(const bf16x8*)&afrag[((ti * 4 + ks) * 64 + lane) * 8];
#pragma unroll
  for (int q = 0; q < 3; q++) {
    int nt = 3 * w + q;
    int jcol = nt * 16 + (lane & 15);
#pragma unroll
    for (int ti = 0; ti < 2; ti++) {
      f32x4 accA = {}, accB = {};
      accA = __builtin_amdgcn_mfma_f32_16x16x32_bf16(a[ti][0], Bf[q][0], accA, 0, 0, 0);
      accA = __builtin_amdgcn_mfma_f32_16x16x32_bf16(a[ti][1], Bf[q][1], accA, 0, 0, 0);
      accB = __builtin_amdgcn_mfma_f32_16x16x32_bf16(a[ti][2], Bf[q][2], accB, 0, 0, 0);
      accB = __builtin_amdgcn_mfma_f32_16x16x32_bf16(a[ti][3], Bf[q][3], accB, 0, 0, 0);
      int nrow = ti * 16 + ((lane >> 4) << 2);
      if (nt < 8) {
#pragma unroll
        for (int rr = 0; rr < 4; rr++) S[(nrow + rr) * 196 + jcol] = accA[rr] + accB[rr];
      } else {
#pragma unroll
        for (int rr = 0; rr < 4; rr++) {
          S[(nrow + rr) * 196 + jcol] = accA[rr];
          SHn[(nrow + rr) * 68 + (jcol - 128)] = accB[rr];
        }
      }
    }
  }
  __syncthreads();

  if (valid) {
    float res[8];
#pragma unroll
    for (int jj = 0; jj < 8; jj++) {
      int j = d0 + jj;
      float gr = S[n * 196 + j] + bih[j] + bhh[j];
      float gz = S[n * 196 + 64 + j] + bih[64 + j] + bhh[64 + j];
      float gin = S[n * 196 + 128 + j] + bih[128 + j];
      float ghn = SHn[n * 68 + j] + bhh[128 + j];
      float rg = 1.f / (1.f + __expf(-gr));
      float zg = 1.f / (1.f + __expf(-gz));
      float ng = tanhf(gin + rg * ghn);
      float h = (1.f - zg) * ng + zg * mv[jj];
      res[jj] = (dn > 0.f) ? h : xv[jj];
    }
    float4* op = (float4*)(out + (size_t)node * 64 + d0);
    op[0] = make_float4(res[0], res[1], res[2], res[3]);
    op[1] = make_float4(res[4], res[5], res[6], res[7]);
  }
}

extern "C" void kernel_launch(void* const* d_in, const int* in_sizes, int n_in,
                              void* d_out, int out_size, void* d_ws, size_t ws_size,
                              hipStream_t stream) {
  const float* x = (const float*)d_in[0];
  const unsigned* eidx = (const unsigned*)d_in[1];
  const float* ew = (const float*)d_in[2];
  const float* W1 = (const float*)d_in[3];
  const float* b1 = (const float*)d_in[4];
  const float* W2 = (const float*)d_in[5];
  const float* b2 = (const float*)d_in[6];
  const float* Wl = (const float*)d_in[7];
  const float* bl = (const float*)d_in[8];
  const float* Wih = (const float*)d_in[9];
  const float* bih = (const float*)d_in[10];
  const float* Whh = (const float*)d_in[11];
  const float* bhh = (const float*)d_in[12];
  float* out = (float*)d_out;

  float* lin_x = (float*)d_ws;                 // N*D
  float* scores = lin_x + (size_t)NN * DD;     // E
  int* srcA = (int*)(scores + EE);             // E
  int* dstA = srcA + EE;                       // E
  float* msgU = (float*)(dstA + EE);           // N*D
  float* denom = msgU + (size_t)NN * DD;       // N
  unsigned short* Bpk = (unsigned short*)(denom + NN);    // 3200*8
  float* b1p = (float*)(Bpk + 25600);          // 160
  float* w2p = b1p + 160;                      // 160
  unsigned short* Bg = (unsigned short*)(w2p + 160);      // 3072*8

  // zero msgU | denom (contiguous)
  hipMemsetAsync(msgU, 0, (size_t)(NN * DD + NN) * sizeof(float), stream);

  cvt_idx<<<(EE + 255) / 256, 256, 0, stream>>>(eidx, srcA, dstA);
  pack_w1<<<13, 256, 0, stream>>>(W1, b1, W2, Bpk, b1p, w2p);
  pack_gru<<<12, 256, 0, stream>>>(Wih, Whh, Bg);
  lin_kernel<<<(NN + 3) / 4, 256, 0, stream>>>(x, Wl, bl, lin_x);
  att_mfma<<<2048, 256, 0, stream>>>(x, ew, srcA, dstA, Bpk, b1p, w2p, b2, scores);
  exp_msg<<<2048, 256, 0, stream>>>(scores, srcA, dstA, lin_x, denom, msgU);
  gru_mfma<<<(NN + 31) / 32, 256, 0, stream>>>(x, msgU, denom, Bg, bih, bhh, out);
}